// Round 1
// 610.867 us; speedup vs baseline: 3.0867x; 3.0867x over previous
//
#include <hip/hip_runtime.h>

typedef unsigned short u16;
typedef unsigned int   u32;
typedef float f32x4  __attribute__((ext_vector_type(4)));
typedef short bf16x8 __attribute__((ext_vector_type(8)));

#define CCH  64
#define HH   512
#define WWD  512
#define WS_  8
#define NWIN 16384

// Pre-packed weights: 32 KB of bf16 B-fragments + 1 KB fp32 biases.
// frag layout: [( (m*4+to)*2+kk )][lane][8 bf16] = W_m[16*to+(lane&15)][kk*32+(lane>>4)*8 + e]
__device__ __align__(16) unsigned char g_wprep[32768 + 1024];

__device__ __forceinline__ u16 f2bf(float f) {
    union { float f; u32 u; } v; v.f = f;
    u32 r = v.u + 0x7fffu + ((v.u >> 16) & 1u);
    return (u16)(r >> 16);
}
__device__ __forceinline__ u32 pack2(float a, float b) {
    return (u32)f2bf(a) | ((u32)f2bf(b) << 16);
}

// ---------------- LDS layout (65536 B total) ----------------
// [    0,  8192)  s_x  : bf16 [t][c], swizzled
// [ 8192, 24576)  Q(8K) K(8K) as bf16 flat [t][o]; later reused per-wave as X2 (f32 [tr][c])
// [24576, 32768)  VT   : bf16 [h][d][s2], swizzled by d
// [32768, 65536)  per-wave 8KB slabs: P (bf16 [s][s2]) then ybuf (f32 [o][19])
__device__ __forceinline__ u32 swz8(u32 t) { return (t ^ (t >> 3)) & 7u; }
__device__ __forceinline__ u32 sx_off(u32 t, u32 c) {
    return ((t << 7) + (c << 1)) ^ (swz8(t) << 4);
}
__device__ __forceinline__ u32 qk_off(u32 elem) {          // elem = t*64 + o
    u32 t = elem >> 6;
    return (elem << 1) ^ (swz8(t) << 4);
}
__device__ __forceinline__ u32 vt_off(u32 h, u32 d, u32 s2) {
    return ((h << 11) + (d << 7) + (s2 << 1)) ^ (swz8(d) << 4);
}
__device__ __forceinline__ u32 p_off(u32 s, u32 s2) {
    return ((s << 7) + (s2 << 1)) ^ (swz8(s) << 4);
}
__device__ __forceinline__ u32 x2_off(u32 w, u32 tr, u32 c) {   // f32, rows 256B, in QK region
    u32 base = 8192u + ((tr >> 3) << 13) + (w << 11);
    u32 b = ((tr & 7) << 8) + (c << 2);
    return base + (b ^ (swz8(tr) << 5));
}

// ---------------- prep kernel: fp32 weights -> bf16 MFMA fragments ----------------
__global__ void wmsa_prep(const float* wq, const float* wk, const float* wv, const float* wp,
                          const float* bq, const float* bk, const float* bv, const float* bp)
{
    int tid = threadIdx.x;
    #pragma unroll
    for (int q = 0; q < 8; ++q) {
        int cid = q * 256 + tid;                 // 2048 chunks of 16 B
        int l  = cid & 63;
        int kk = (cid >> 6) & 1;
        int to = (cid >> 7) & 3;
        int m  = (cid >> 9) & 3;
        const float* wm = (m == 0) ? wq : (m == 1) ? wk : (m == 2) ? wv : wp;
        int o  = 16 * to + (l & 15);
        int c0 = kk * 32 + (l >> 4) * 8;
        const float4* src = (const float4*)(wm + o * 64 + c0);
        float4 a = src[0], b2 = src[1];
        uint4 pk = { pack2(a.x, a.y), pack2(a.z, a.w), pack2(b2.x, b2.y), pack2(b2.z, b2.w) };
        *(uint4*)(g_wprep + (size_t)cid * 16) = pk;
    }
    const float* bsrc = (tid < 64) ? bq : (tid < 128) ? bk : (tid < 192) ? bv : bp;
    ((float*)(g_wprep + 32768))[tid] = bsrc[tid & 63];
}

// ---------------- main kernel ----------------
__global__ __launch_bounds__(256, 2) void wmsa_kernel(
    const float* __restrict__ x, float* __restrict__ y)
{
    __shared__ __align__(16) unsigned char smem[65536];

    const int tid  = threadIdx.x;
    const int lane = tid & 63;
    const int w    = tid >> 6;       // wave id == head id
    const int lg   = lane >> 4;      // k-group / row-group
    const int lr   = lane & 15;

    // XCD-contiguous bijective remap (16384 % 8 == 0): XCD k gets windows [k*2048, (k+1)*2048)
    const int bid = blockIdx.x;
    const int win = ((bid & 7) << 11) | (bid >> 3);
    const int b   = win >> 12;
    const int wh  = (win >> 6) & 63;
    const int wwi = win & 63;

    const float* __restrict__ gb = (const float*)(g_wprep + 32768);
    const f32x4 zf = {0.f, 0.f, 0.f, 0.f};

    // ---- stage x window -> s_x bf16 [t][c] swizzled ----
    #pragma unroll
    for (int it = 0; it < 2; ++it) {
        int e = it * 256 + tid;                   // 512 rows (c,i) of 8 floats
        int c = e >> 3;
        int i = e & 7;
        const float4* src = (const float4*)(x +
            ((((size_t)b * CCH + c) * HH + wh * WS_ + i) * WWD + wwi * WS_));
        float4 v0 = src[0], v1 = src[1];
        u16 pk[8] = { f2bf(v0.x), f2bf(v0.y), f2bf(v0.z), f2bf(v0.w),
                      f2bf(v1.x), f2bf(v1.y), f2bf(v1.z), f2bf(v1.w) };
        #pragma unroll
        for (int j = 0; j < 8; ++j) {
            int t = i * 8 + j;
            *(u16*)(smem + sx_off((u32)t, (u32)c)) = pk[j];
        }
    }
    __syncthreads();
    // ---- everything below is wave-local (no barriers until the y epilogue) ----

    // A-fragments of X for the projections: row t = 16w + lr, k-slices along c
    bf16x8 ax0, ax1;
    {
        int tA = w * 16 + lr;
        ax0 = *(const bf16x8*)(smem + sx_off((u32)tA, (u32)(lg * 8)));
        ax1 = *(const bf16x8*)(smem + sx_off((u32)tA, (u32)(32 + lg * 8)));
    }

    // ---- Q, K projections -> swizzled bf16 slabs ----
    #pragma unroll
    for (int m = 0; m < 2; ++m) {
        u32 rbase = 8192u + (u32)m * 8192u;
        #pragma unroll
        for (int to = 0; to < 4; ++to) {
            bf16x8 b0 = *(const bf16x8*)(g_wprep + ((((m * 4 + to) * 2 + 0) * 64 + lane) << 4));
            bf16x8 b1 = *(const bf16x8*)(g_wprep + ((((m * 4 + to) * 2 + 1) * 64 + lane) << 4));
            f32x4 acc = __builtin_amdgcn_mfma_f32_16x16x32_bf16(ax0, b0, zf, 0, 0, 0);
            acc = __builtin_amdgcn_mfma_f32_16x16x32_bf16(ax1, b1, acc, 0, 0, 0);
            float bias = gb[m * 64 + to * 16 + lr];
            #pragma unroll
            for (int r = 0; r < 4; ++r) {
                int t = w * 16 + lg * 4 + r;
                int o = to * 16 + lr;
                *(u16*)(smem + rbase + qk_off((u32)(t * 64 + o))) = f2bf(acc[r] + bias);
            }
        }
    }

    // ---- V projection -> transposed per-head slab VT[h][d][s2] ----
    {
        f32x4 av[4]; float bv4[4];
        #pragma unroll
        for (int to = 0; to < 4; ++to) {
            bf16x8 b0 = *(const bf16x8*)(g_wprep + ((((2 * 4 + to) * 2 + 0) * 64 + lane) << 4));
            bf16x8 b1 = *(const bf16x8*)(g_wprep + ((((2 * 4 + to) * 2 + 1) * 64 + lane) << 4));
            f32x4 acc = __builtin_amdgcn_mfma_f32_16x16x32_bf16(ax0, b0, zf, 0, 0, 0);
            acc = __builtin_amdgcn_mfma_f32_16x16x32_bf16(ax1, b1, acc, 0, 0, 0);
            av[to] = acc;
            bv4[to] = gb[128 + to * 16 + lr];
        }
        // lane holds V[t=16w+4g+r][o=16to+lr] -> (d=lr, s2=16g+4r+to): pack 4 consecutive s2
        #pragma unroll
        for (int r = 0; r < 4; ++r) {
            uint2 u;
            u.x = pack2(av[0][r] + bv4[0], av[1][r] + bv4[1]);
            u.y = pack2(av[2][r] + bv4[2], av[3][r] + bv4[3]);
            *(uint2*)(smem + 24576u + vt_off((u32)w, (u32)lr, (u32)(lg * 16 + r * 4))) = u;
        }
    }

    // ---- scores: S^T tiles = mfma(K, Q), K=16 zero-padded to 32 ----
    bf16x8 kz = {0, 0, 0, 0, 0, 0, 0, 0};
    bf16x8 kf[4], qf[4];
    const bool gact = (lg < 2);
    #pragma unroll
    for (int tt = 0; tt < 4; ++tt) {
        int srow = tt * 16 + lr;
        kf[tt] = kz; qf[tt] = kz;
        if (gact) {
            u32 e = (u32)(w * 1024 + srow * 16 + lg * 8);
            qf[tt] = *(const bf16x8*)(smem + 8192u  + qk_off(e));
            kf[tt] = *(const bf16x8*)(smem + 16384u + qk_off(e));
        }
    }
    f32x4 sacc[4][4];   // [s2-tile][s-tile]; lane: S[s=16*t1+lr][s2=16*t2+4*lg+r]
    #pragma unroll
    for (int t2 = 0; t2 < 4; ++t2)
        #pragma unroll
        for (int t1 = 0; t1 < 4; ++t1)
            sacc[t2][t1] = __builtin_amdgcn_mfma_f32_16x16x32_bf16(kf[t2], qf[t1], zf, 0, 0, 0);

    // ---- softmax (in-register; rows distributed 4 lanes apart) + P -> LDS ----
    const float ksc = 0.25f * 1.44269504088896341f;   // scale * log2(e)
    const u32 pslab = 32768u + (u32)w * 8192u;
    #pragma unroll
    for (int t1 = 0; t1 < 4; ++t1) {
        float mx = -3.4e38f;
        #pragma unroll
        for (int t2 = 0; t2 < 4; ++t2)
            #pragma unroll
            for (int r = 0; r < 4; ++r) mx = fmaxf(mx, sacc[t2][t1][r]);
        mx = fmaxf(mx, __shfl_xor(mx, 16));
        mx = fmaxf(mx, __shfl_xor(mx, 32));
        float sum = 0.f;
        #pragma unroll
        for (int t2 = 0; t2 < 4; ++t2)
            #pragma unroll
            for (int r = 0; r < 4; ++r) {
                float e = exp2f((sacc[t2][t1][r] - mx) * ksc);
                sacc[t2][t1][r] = e;
                sum += e;
            }
        sum += __shfl_xor(sum, 16);
        sum += __shfl_xor(sum, 32);
        float inv = 1.0f / sum;
        int s = t1 * 16 + lr;
        #pragma unroll
        for (int t2 = 0; t2 < 4; ++t2) {
            uint2 u;
            u.x = pack2(sacc[t2][t1][0] * inv, sacc[t2][t1][1] * inv);
            u.y = pack2(sacc[t2][t1][2] * inv, sacc[t2][t1][3] * inv);
            *(uint2*)(smem + pslab + p_off((u32)s, (u32)(t2 * 16 + lg * 4))) = u;
        }
    }

    // ---- PV: out = mfma(P, V) ; write X2 (f32) into this wave's dead Q/K slab ----
    {
        bf16x8 vf0 = *(const bf16x8*)(smem + 24576u + vt_off((u32)w, (u32)lr, (u32)(lg * 8)));
        bf16x8 vf1 = *(const bf16x8*)(smem + 24576u + vt_off((u32)w, (u32)lr, (u32)(32 + lg * 8)));
        #pragma unroll
        for (int t1 = 0; t1 < 4; ++t1) {
            bf16x8 p0 = *(const bf16x8*)(smem + pslab + p_off((u32)(t1 * 16 + lr), (u32)(lg * 8)));
            bf16x8 p1 = *(const bf16x8*)(smem + pslab + p_off((u32)(t1 * 16 + lr), (u32)(32 + lg * 8)));
            f32x4 acc = __builtin_amdgcn_mfma_f32_16x16x32_bf16(p0, vf0, zf, 0, 0, 0);
            acc = __builtin_amdgcn_mfma_f32_16x16x32_bf16(p1, vf1, acc, 0, 0, 0);
            int tr = t1 * 4 + lg;     // row (t & 15); cols c = r*16 + lr
            #pragma unroll
            for (int r = 0; r < 4; ++r)
                *(float*)(smem + x2_off((u32)w, (u32)tr, (u32)(r * 16 + lr))) = acc[r];
        }
    }

    // ---- output projection: A = X2 (f32 -> bf16), B = Wp frags; ybuf [o][19] f32 ----
    {
        bf16x8 ao0, ao1;
        {
            const float4* xp = (const float4*)(smem + x2_off((u32)w, (u32)lr, (u32)(lg * 8)));
            float4 v0 = xp[0], v1 = xp[1];
            uint4 uu = { pack2(v0.x, v0.y), pack2(v0.z, v0.w), pack2(v1.x, v1.y), pack2(v1.z, v1.w) };
            ao0 = *(bf16x8*)&uu;
            const float4* xq = (const float4*)(smem + x2_off((u32)w, (u32)lr, (u32)(32 + lg * 8)));
            float4 v2 = xq[0], v3 = xq[1];
            uint4 vv = { pack2(v2.x, v2.y), pack2(v2.z, v2.w), pack2(v3.x, v3.y), pack2(v3.z, v3.w) };
            ao1 = *(bf16x8*)&vv;
        }
        #pragma unroll
        for (int to = 0; to < 4; ++to) {
            bf16x8 b0 = *(const bf16x8*)(g_wprep + ((((3 * 4 + to) * 2 + 0) * 64 + lane) << 4));
            bf16x8 b1 = *(const bf16x8*)(g_wprep + ((((3 * 4 + to) * 2 + 1) * 64 + lane) << 4));
            f32x4 acc = __builtin_amdgcn_mfma_f32_16x16x32_bf16(ao0, b0, zf, 0, 0, 0);
            acc = __builtin_amdgcn_mfma_f32_16x16x32_bf16(ao1, b1, acc, 0, 0, 0);
            #pragma unroll
            for (int r = 0; r < 4; ++r) {
                int o  = to * 16 + lr;
                int tq = lg * 4 + r;
                *(float*)(smem + pslab + (u32)((o * 19 + tq) << 2)) = acc[r];
            }
        }
    }
    __syncthreads();

    // ---- epilogue: lane = token (i,j); 16 o's per lane -> 8x32B-per-line stores ----
    {
        int i = lane >> 3, j = lane & 7;
        int t = i * 8 + j;
        u32 srcslab = 32768u + (u32)(t >> 4) * 8192u;
        int tq = t & 15;
        size_t ybase = (((size_t)b * CCH * HH) + (size_t)(wh * WS_ + i)) * WWD + (size_t)(wwi * WS_ + j);
        #pragma unroll
        for (int oo = 0; oo < 16; ++oo) {
            int o = w * 16 + oo;
            float v = *(const float*)(smem + srcslab + (u32)((o * 19 + tq) << 2)) + gb[192 + o];
            y[ybase + (size_t)o * (HH * (size_t)WWD)] = v;
        }
    }
}

extern "C" void kernel_launch(void* const* d_in, const int* in_sizes, int n_in,
                              void* d_out, int out_size, void* d_ws, size_t ws_size,
                              hipStream_t stream) {
    const float* x  = (const float*)d_in[0];
    const float* wq = (const float*)d_in[1];
    const float* bq = (const float*)d_in[2];
    const float* wk = (const float*)d_in[3];
    const float* bk = (const float*)d_in[4];
    const float* wv = (const float*)d_in[5];
    const float* bv = (const float*)d_in[6];
    const float* wp = (const float*)d_in[7];
    const float* bp = (const float*)d_in[8];
    float* y = (float*)d_out;

    hipLaunchKernelGGL(wmsa_prep, dim3(1), dim3(256), 0, stream,
                       wq, wk, wv, wp, bq, bk, bv, bp);
    hipLaunchKernelGGL(wmsa_kernel, dim3(NWIN), dim3(256), 0, stream, x, y);
}

// Round 4
// 560.089 us; speedup vs baseline: 3.3665x; 1.0907x over previous
//
#include <hip/hip_runtime.h>

typedef unsigned short u16;
typedef unsigned int   u32;
typedef float f32x4   __attribute__((ext_vector_type(4)));
typedef short bf16x8  __attribute__((ext_vector_type(8)));
typedef short bf16x4s __attribute__((ext_vector_type(4)));

#define CCH  64
#define HH   512
#define WWD  512
#define WS_  8
#define NWIN 16384

// Pre-packed weights: 32 KB of bf16 B-fragments + 1 KB fp32 biases.
// frag layout: [( (m*4+to)*2+kk )][lane][8 bf16] = W_m[16*to+(lane&15)][kk*32+(lane>>4)*8 + e]
__device__ __align__(16) unsigned char g_wprep[32768 + 1024];

// ---- bf16 converts via HW v_cvt_pk_bf16_f32 (RNE) ----
__device__ __forceinline__ u16 f2bfh(float f) {
    __bf16 h = (__bf16)f;
    union { __bf16 b; u16 u; } cv; cv.b = h; return cv.u;
}
__device__ __forceinline__ u32 pack2(float a, float b) {
    return (u32)f2bfh(a) | ((u32)f2bfh(b) << 16);
}
__device__ __forceinline__ bf16x4s mk4(float a, float b, float c, float d) {
    bf16x4s v;
    v[0] = (short)f2bfh(a); v[1] = (short)f2bfh(b);
    v[2] = (short)f2bfh(c); v[3] = (short)f2bfh(d);
    return v;
}

// 16x16x16 bf16 MFMA (K=16): A row=lane&15,k=(lane>>4)*4+e; D col=lane&15,row=(lane>>4)*4+r
__device__ __forceinline__ f32x4 mfma16(bf16x4s a, bf16x4s b, f32x4 c) {
#if __has_builtin(__builtin_amdgcn_mfma_f32_16x16x16bf16_1k)
    return __builtin_amdgcn_mfma_f32_16x16x16bf16_1k(a, b, c, 0, 0, 0);
#else
    asm("v_mfma_f32_16x16x16_bf16 %0, %1, %2, %0" : "+v"(c) : "v"(a), "v"(b));
    return c;
#endif
}

// ---------------- LDS layout (32768 B) ----------------
// [    0,  8192)  s_x : bf16 [t][c], swizzled          (dead after ax loads)
// [ 8192, 24576)  Q(8K) K(8K) bf16 flat [t][o]; per-wave X2 (f32) reuses it
// [24576, 32768)  VT  : bf16 [h][d][s2], swizzled
// ybuf (f32, 4 slabs x 1032 words) reuses [0, 16512) after barrier2
__device__ __forceinline__ u32 swz8(u32 t) { return (t ^ (t >> 3)) & 7u; }
__device__ __forceinline__ u32 sx_off(u32 t, u32 c) {
    return ((t << 7) + (c << 1)) ^ (swz8(t) << 4);
}
__device__ __forceinline__ u32 qk_off(u32 e) {            // e = t*64 + o
    u32 t = e >> 6;
    return (e << 1) ^ (((t >> 2) & 3u) << 4);             // key: t>>2 (varies with lg on stores, uniform on frag reads)
}
__device__ __forceinline__ u32 vt_off(u32 h, u32 d, u32 s2) {
    return (h << 11) + (d << 7) + (((s2 << 1) ^ ((d & 15u) << 3)) & 127u);
}
__device__ __forceinline__ u32 x2_off(u32 w, u32 tr, u32 c) {   // f32, in QK region
    u32 base = 8192u + ((tr >> 3) << 13) + (w << 11);
    u32 b = ((tr & 7) << 8) + (c << 2);
    return base + (b ^ (swz8(tr) << 5));
}

// ---------------- prep kernel: fp32 weights -> bf16 MFMA fragments ----------------
__global__ void wmsa_prep(const float* wq, const float* wk, const float* wv, const float* wp,
                          const float* bq, const float* bk, const float* bv, const float* bp)
{
    int tid = threadIdx.x;
    #pragma unroll
    for (int q = 0; q < 8; ++q) {
        int cid = q * 256 + tid;                 // 2048 chunks of 16 B
        int l  = cid & 63;
        int kk = (cid >> 6) & 1;
        int to = (cid >> 7) & 3;
        int m  = (cid >> 9) & 3;
        const float* wm = (m == 0) ? wq : (m == 1) ? wk : (m == 2) ? wv : wp;
        int o  = 16 * to + (l & 15);
        int c0 = kk * 32 + (l >> 4) * 8;
        const float4* src = (const float4*)(wm + o * 64 + c0);
        float4 a = src[0], b2 = src[1];
        uint4 pk = { pack2(a.x, a.y), pack2(a.z, a.w), pack2(b2.x, b2.y), pack2(b2.z, b2.w) };
        *(uint4*)(g_wprep + (size_t)cid * 16) = pk;
    }
    const float* bsrc = (tid < 64) ? bq : (tid < 128) ? bk : (tid < 192) ? bv : bp;
    ((float*)(g_wprep + 32768))[tid] = bsrc[tid & 63];
}

// ---------------- main kernel ----------------
__global__ __launch_bounds__(256, 4) void wmsa_kernel(
    const float* __restrict__ x, float* __restrict__ y)
{
    __shared__ __align__(16) unsigned char smem[32768];

    const int tid  = threadIdx.x;
    const int lane = tid & 63;
    const int w    = tid >> 6;       // wave id == head id
    const int lg   = lane >> 4;      // k-group / row-group
    const int lr   = lane & 15;

    // XCD-contiguous bijective remap (16384 % 8 == 0)
    const int bid = blockIdx.x;
    const int win = ((bid & 7) << 11) | (bid >> 3);
    const int b   = win >> 12;
    const int wh  = (win >> 6) & 63;
    const int wwi = win & 63;

    const float* __restrict__ gb = (const float*)(g_wprep + 32768);
    const f32x4 zf = {0.f, 0.f, 0.f, 0.f};

    // ---- stage x window -> s_x bf16 [t][c] swizzled ----
    #pragma unroll
    for (int it = 0; it < 2; ++it) {
        int e = it * 256 + tid;                   // 512 rows (c,i) of 8 floats
        int c = e >> 3;
        int i = e & 7;
        const float4* src = (const float4*)(x +
            ((((size_t)b * CCH + c) * HH + wh * WS_ + i) * WWD + wwi * WS_));
        float4 v0 = src[0], v1 = src[1];
        u16 pk[8] = { f2bfh(v0.x), f2bfh(v0.y), f2bfh(v0.z), f2bfh(v0.w),
                      f2bfh(v1.x), f2bfh(v1.y), f2bfh(v1.z), f2bfh(v1.w) };
        #pragma unroll
        for (int j = 0; j < 8; ++j) {
            int t = i * 8 + j;
            *(u16*)(smem + sx_off((u32)t, (u32)c)) = pk[j];
        }
    }
    __syncthreads();
    // ---- wave-local from here until the epilogue barriers ----

    // A-fragments of X: row t = 16w + lr, k-slices along c
    bf16x8 ax0, ax1;
    {
        int tA = w * 16 + lr;
        ax0 = *(const bf16x8*)(smem + sx_off((u32)tA, (u32)(lg * 8)));
        ax1 = *(const bf16x8*)(smem + sx_off((u32)tA, (u32)(32 + lg * 8)));
    }

    // ---- Q, K projections -> bf16 slabs ----
    #pragma unroll
    for (int m = 0; m < 2; ++m) {
        u32 rbase = 8192u + (u32)m * 8192u;
        #pragma unroll
        for (int to = 0; to < 4; ++to) {
            bf16x8 b0 = *(const bf16x8*)(g_wprep + ((((m * 4 + to) * 2 + 0) * 64 + lane) << 4));
            bf16x8 b1 = *(const bf16x8*)(g_wprep + ((((m * 4 + to) * 2 + 1) * 64 + lane) << 4));
            f32x4 acc = __builtin_amdgcn_mfma_f32_16x16x32_bf16(ax0, b0, zf, 0, 0, 0);
            acc = __builtin_amdgcn_mfma_f32_16x16x32_bf16(ax1, b1, acc, 0, 0, 0);
            float bias = gb[m * 64 + to * 16 + lr];
            #pragma unroll
            for (int r = 0; r < 4; ++r) {
                int t = w * 16 + lg * 4 + r;
                int o = to * 16 + lr;
                *(u16*)(smem + rbase + qk_off((u32)(t * 64 + o))) = f2bfh(acc[r] + bias);
            }
        }
    }

    // ---- V projection -> transposed per-head slab VT[h][d][s2] ----
    {
        f32x4 av[4]; float bv4[4];
        #pragma unroll
        for (int to = 0; to < 4; ++to) {
            bf16x8 b0 = *(const bf16x8*)(g_wprep + ((((2 * 4 + to) * 2 + 0) * 64 + lane) << 4));
            bf16x8 b1 = *(const bf16x8*)(g_wprep + ((((2 * 4 + to) * 2 + 1) * 64 + lane) << 4));
            f32x4 acc = __builtin_amdgcn_mfma_f32_16x16x32_bf16(ax0, b0, zf, 0, 0, 0);
            acc = __builtin_amdgcn_mfma_f32_16x16x32_bf16(ax1, b1, acc, 0, 0, 0);
            av[to] = acc;
            bv4[to] = gb[128 + to * 16 + lr];
        }
        // lane holds V[t=16w+4lg+r][o=16to+lr] -> (d=lr, s2=16lg+4r+to)
        #pragma unroll
        for (int r = 0; r < 4; ++r) {
            uint2 u;
            u.x = pack2(av[0][r] + bv4[0], av[1][r] + bv4[1]);
            u.y = pack2(av[2][r] + bv4[2], av[3][r] + bv4[3]);
            *(uint2*)(smem + 24576u + vt_off((u32)w, (u32)lr, (u32)(lg * 16 + r * 4))) = u;
        }
    }

    // ---- score fragments (K-dim = d = 16, native 16x16x16) ----
    bf16x4s kf4[4], qf4[4];
    #pragma unroll
    for (int tt = 0; tt < 4; ++tt) {
        u32 e = (u32)(w * 1024 + (tt * 16 + lr) * 16 + lg * 4);
        qf4[tt] = *(const bf16x4s*)(smem + 8192u  + qk_off(e));
        kf4[tt] = *(const bf16x4s*)(smem + 16384u + qk_off(e));
    }
    // PV B-fragments: B[k=4lg+e][col=lr=d] = VT[lr][16t2+4lg+e]
    bf16x4s vfb[4];
    #pragma unroll
    for (int t2 = 0; t2 < 4; ++t2)
        vfb[t2] = *(const bf16x4s*)(smem + 24576u + vt_off((u32)w, (u32)lr, (u32)(t2 * 16 + lg * 4)));

    // ---- fused scores + softmax + PV per s-tile t1 (P never leaves registers) ----
    const float ksc = 0.25f * 1.44269504088896341f;   // 1/sqrt(16) * log2(e)
    #pragma unroll
    for (int t1 = 0; t1 < 4; ++t1) {
        f32x4 sc[4];    // lane: S[s=16t1+lr][s2=16t2+4lg+r]
        #pragma unroll
        for (int t2 = 0; t2 < 4; ++t2)
            sc[t2] = mfma16(kf4[t2], qf4[t1], zf);

        float mx = -3.4e38f;
        #pragma unroll
        for (int t2 = 0; t2 < 4; ++t2)
            #pragma unroll
            for (int r = 0; r < 4; ++r) mx = fmaxf(mx, sc[t2][r]);
        mx = fmaxf(mx, __shfl_xor(mx, 16));
        mx = fmaxf(mx, __shfl_xor(mx, 32));
        float sum = 0.f;
        #pragma unroll
        for (int t2 = 0; t2 < 4; ++t2)
            #pragma unroll
            for (int r = 0; r < 4; ++r) {
                float e = exp2f((sc[t2][r] - mx) * ksc);
                sc[t2][r] = e; sum += e;
            }
        sum += __shfl_xor(sum, 16);
        sum += __shfl_xor(sum, 32);
        float inv = 1.0f / sum;

        // P tile IS the 16x16x16 A-fragment: row=lr, k=4lg+r
        f32x4 oacc = zf;
        #pragma unroll
        for (int t2 = 0; t2 < 4; ++t2) {
            bf16x4s pf = mk4(sc[t2][0] * inv, sc[t2][1] * inv,
                             sc[t2][2] * inv, sc[t2][3] * inv);
            oacc = mfma16(pf, vfb[t2], oacc);
        }
        // D[row=4lg+r][col=lr] = O[s=16t1+4lg+r][d=lr] -> token tq=4t1+lg, c=r*16+lr
        int tr = t1 * 4 + lg;
        #pragma unroll
        for (int r = 0; r < 4; ++r)
            *(float*)(smem + x2_off((u32)w, (u32)tr, (u32)(r * 16 + lr))) = oacc[r];
    }

    // ---- output projection: A = X2 (f32 -> bf16), B = Wp frags ----
    f32x4 racc[4];
    {
        bf16x8 ao0, ao1;
        {
            const float4* xp = (const float4*)(smem + x2_off((u32)w, (u32)lr, (u32)(lg * 8)));
            float4 v0 = xp[0], v1 = xp[1];
            uint4 uu = { pack2(v0.x, v0.y), pack2(v0.z, v0.w), pack2(v1.x, v1.y), pack2(v1.z, v1.w) };
            ao0 = *(bf16x8*)&uu;
            const float4* xq = (const float4*)(smem + x2_off((u32)w, (u32)lr, (u32)(32 + lg * 8)));
            float4 v2 = xq[0], v3 = xq[1];
            uint4 vv = { pack2(v2.x, v2.y), pack2(v2.z, v2.w), pack2(v3.x, v3.y), pack2(v3.z, v3.w) };
            ao1 = *(bf16x8*)&vv;
        }
        #pragma unroll
        for (int to = 0; to < 4; ++to) {
            bf16x8 b0 = *(const bf16x8*)(g_wprep + ((((3 * 4 + to) * 2 + 0) * 64 + lane) << 4));
            bf16x8 b1 = *(const bf16x8*)(g_wprep + ((((3 * 4 + to) * 2 + 1) * 64 + lane) << 4));
            f32x4 acc = __builtin_amdgcn_mfma_f32_16x16x32_bf16(ao0, b0, zf, 0, 0, 0);
            racc[to] = __builtin_amdgcn_mfma_f32_16x16x32_bf16(ao1, b1, acc, 0, 0, 0);
        }
    }
    __syncthreads();   // all waves done reading X2/s_x -> safe to overlay ybuf

    // ---- ybuf: f32 slabs [wave][o][tq], 1032-word stride (bank-friendly) ----
    {
        #pragma unroll
        for (int to = 0; to < 4; ++to) {
            u32 word = (u32)w * 1032u + (u32)((to * 16 + lr) * 16 + lg * 4);
            *(f32x4*)(smem + (word << 2)) = racc[to];   // tq = 4lg..4lg+3
        }
    }
    __syncthreads();

    // ---- epilogue: lane = token (i,j); 16 o's per lane -> 8x32B-per-line stores ----
    {
        int i = lane >> 3, j = lane & 7;
        u32 base = (u32)(lane >> 4) * 1032u + (u32)(lane & 15);
        size_t ybase = (((size_t)b * CCH * HH) + (size_t)(wh * WS_ + i)) * WWD + (size_t)(wwi * WS_ + j);
        #pragma unroll
        for (int oo = 0; oo < 16; ++oo) {
            int o = w * 16 + oo;
            float v = ((const float*)smem)[base + ((u32)o << 4)] + gb[192 + o];
            y[ybase + (size_t)o * (HH * (size_t)WWD)] = v;
        }
    }
}

extern "C" void kernel_launch(void* const* d_in, const int* in_sizes, int n_in,
                              void* d_out, int out_size, void* d_ws, size_t ws_size,
                              hipStream_t stream) {
    const float* x  = (const float*)d_in[0];
    const float* wq = (const float*)d_in[1];
    const float* bq = (const float*)d_in[2];
    const float* wk = (const float*)d_in[3];
    const float* bk = (const float*)d_in[4];
    const float* wv = (const float*)d_in[5];
    const float* bv = (const float*)d_in[6];
    const float* wp = (const float*)d_in[7];
    const float* bp = (const float*)d_in[8];
    float* y = (float*)d_out;

    hipLaunchKernelGGL(wmsa_prep, dim3(1), dim3(256), 0, stream,
                       wq, wk, wv, wp, bq, bk, bv, bp);
    hipLaunchKernelGGL(wmsa_kernel, dim3(NWIN), dim3(256), 0, stream, x, y);
}